// Round 3
// baseline (97246.844 us; speedup 1.0000x reference)
//
#include <hip/hip_runtime.h>
#include <cstddef>

// ---------------- problem constants ----------------
#define DIMD   1024
#define DIMH   512
#define NB     16
#define MB     8          // batch
#define SEQ    2048
#define TSTEPS 2048       // extrapolation steps
#define NWG    256
#define TPB    256

// ws layout (float offsets)
#define OFF_E   0          // 1024x512
#define OFF_Q1  524288     // 16x1024
#define OFF_Q2  540672     // 16x1024
#define OFF_Q3  557056     // 16x512
#define OFF_K2  565248     // 512
#define OFF_N0  565760     // 2 x 8 x 1024
#define OFF_H1  582144     // 8 x 1024
#define OFF_H2  590336     // 8 x 512
#define OFF_CTR 594432     // 4097 u32
#define WS_FLOATS (OFF_CTR + 4200)

// LDS layout (float offsets), total 32618 floats = 130472 bytes
#define S_D1A 0
#define S_D1B 4096
#define S_D2  8192
#define S_W1  12288
#define S_E   14336
#define S_W2  16384
#define S_H2  24576      // [8][516]
#define S_RED 28704      // [256][13]
#define S_C   32032      // [2][128]
#define S_Q1  32288      // [4][16]
#define S_Q2  32352
#define S_Q3  32416      // [2][16]
#define S_B   32448      // [4][16]
#define S_CUR 32512      // [4][8]
#define S_A   32544      // [2][8]
#define S_N0S 32560      // [4][8]
#define S_BD1 32592
#define S_BD2 32596
#define S_K2  32600
#define S_B2  32602
#define SMEM_FLOATS 32618
#define SMEM_BYTES  (SMEM_FLOATS*4)

__device__ __forceinline__ int swz(int k) { return k ^ ((k >> 4) & 7); }

#define GETQ(v,q) ((q)==0?(v).x:(q)==1?(v).y:(q)==2?(v).z:(v).w)

// ---------------- copy x into out[:, :2048, :] ----------------
__global__ __launch_bounds__(256) void copy_x_kernel(const float4* __restrict__ x,
                                                     float4* __restrict__ out) {
    const int total = MB * SEQ * (DIMD/4); // 4,194,304
    for (int i = blockIdx.x*256 + threadIdx.x; i < total; i += 4096*256) {
        int j = i & 255;
        int s = (i >> 8) & 2047;
        int m = i >> 19;
        out[((size_t)m*4096 + s)*256 + j] = x[i];
    }
}

// ---------------- E = D2 @ W1 (1024x512) ----------------
__global__ __launch_bounds__(256) void gemm_E_kernel(const float* __restrict__ A,
                                                     const float* __restrict__ Bw,
                                                     float* __restrict__ C) {
    __shared__ float As[64][17];
    __shared__ float Bs[16][65];
    const int r0 = blockIdx.x * 64, c0 = blockIdx.y * 64;
    const int tx = threadIdx.x & 15, ty = threadIdx.x >> 4;
    float acc[4][4] = {};
    for (int k0 = 0; k0 < 1024; k0 += 16) {
        {
            int row = threadIdx.x >> 2, c4 = (threadIdx.x & 3) * 4;
            float4 av = *(const float4*)&A[(size_t)(r0+row)*1024 + k0 + c4];
            As[row][c4+0]=av.x; As[row][c4+1]=av.y; As[row][c4+2]=av.z; As[row][c4+3]=av.w;
            int row2 = threadIdx.x >> 4, cc = (threadIdx.x & 15) * 4;
            float4 bv = *(const float4*)&Bw[(size_t)(k0+row2)*512 + c0 + cc];
            Bs[row2][cc+0]=bv.x; Bs[row2][cc+1]=bv.y; Bs[row2][cc+2]=bv.z; Bs[row2][cc+3]=bv.w;
        }
        __syncthreads();
        #pragma unroll
        for (int kk = 0; kk < 16; ++kk) {
            float av[4], bv[4];
            #pragma unroll
            for (int u=0;u<4;++u) av[u] = As[ty*4+u][kk];
            #pragma unroll
            for (int v=0;v<4;++v) bv[v] = Bs[kk][tx*4+v];
            #pragma unroll
            for (int u=0;u<4;++u)
                #pragma unroll
                for (int v=0;v<4;++v) acc[u][v] = fmaf(av[u], bv[v], acc[u][v]);
        }
        __syncthreads();
    }
    #pragma unroll
    for (int u=0;u<4;++u)
        #pragma unroll
        for (int v=0;v<4;++v)
            C[(size_t)(r0+ty*4+u)*512 + c0+tx*4+v] = acc[u][v];
}

// ---------------- Q1=B@D1a, Q2=B@D1b, Q3=B@W1, K2=b1+bD2@W1 ----------------
__global__ __launch_bounds__(256) void qk_kernel(const float* __restrict__ Bm,
                                                 const float* __restrict__ D1,
                                                 const float* __restrict__ W1,
                                                 const float* __restrict__ b1,
                                                 const float* __restrict__ bD2,
                                                 float* __restrict__ Q1, float* __restrict__ Q2,
                                                 float* __restrict__ Q3, float* __restrict__ K2) {
    int gid = blockIdx.x*256 + threadIdx.x;
    if (gid < 16384) {
        int i = gid >> 10, j = gid & 1023; float s = 0.f;
        for (int k = 0; k < 1024; ++k) s = fmaf(Bm[i*1024+k], D1[(size_t)k*1024 + j], s);
        Q1[gid] = s;
    } else if (gid < 32768) {
        int g = gid - 16384; int i = g >> 10, j = g & 1023; float s = 0.f;
        for (int k = 0; k < 1024; ++k) s = fmaf(Bm[i*1024+k], D1[(size_t)(1024+k)*1024 + j], s);
        Q2[g] = s;
    } else if (gid < 40960) {
        int g = gid - 32768; int i = g >> 9, c = g & 511; float s = 0.f;
        for (int k = 0; k < 1024; ++k) s = fmaf(Bm[i*1024+k], W1[(size_t)k*512 + c], s);
        Q3[g] = s;
    } else if (gid < 41472) {
        int c = gid - 40960; float s = b1[c];
        for (int k = 0; k < 1024; ++k) s = fmaf(bD2[k], W1[(size_t)k*512 + c], s);
        K2[c] = s;
    }
}

// ---------------- grid barrier ----------------
__device__ __forceinline__ void gbar(unsigned* ctr, int bid, int tid, int& bud) {
    __builtin_amdgcn_fence(__ATOMIC_RELEASE, "agent");
    __syncthreads();
    if (tid == 0) {
        __hip_atomic_fetch_add(&ctr[bid], 1u, __ATOMIC_RELAXED, __HIP_MEMORY_SCOPE_AGENT);
        while (bud > 0) {
            unsigned v = __hip_atomic_load(&ctr[bid], __ATOMIC_RELAXED, __HIP_MEMORY_SCOPE_AGENT);
            if (v >= NWG) break;
            --bud;
            __builtin_amdgcn_s_sleep(2);
        }
    }
    __syncthreads();
    __builtin_amdgcn_fence(__ATOMIC_ACQUIRE, "agent");
}

// ---------------- persistent main kernel ----------------
__global__ __launch_bounds__(256, 1) void main_kernel(
    const float* __restrict__ x, const float* __restrict__ Bm,
    const float* __restrict__ W1, const float* __restrict__ b1,
    const float* __restrict__ W2, const float* __restrict__ b2,
    const float* __restrict__ D1, const float* __restrict__ bD1,
    const float* __restrict__ D2, const float* __restrict__ bD2,
    float* __restrict__ outp,
    const float* __restrict__ E, const float* __restrict__ Q1,
    const float* __restrict__ Q2, const float* __restrict__ Q3,
    const float* __restrict__ K2v,
    float* __restrict__ N0g, float* __restrict__ H1g, float* __restrict__ H2g,
    unsigned* __restrict__ ctr)
{
    extern __shared__ float sm[];
    float* sD1a = sm + S_D1A; float* sD1b = sm + S_D1B; float* sD2 = sm + S_D2;
    float* sW1  = sm + S_W1;  float* sE   = sm + S_E;   float* sW2 = sm + S_W2;
    float* sH2  = sm + S_H2;  float* sRed = sm + S_RED; float* sC  = sm + S_C;
    float* sQ1  = sm + S_Q1;  float* sQ2  = sm + S_Q2;  float* sQ3 = sm + S_Q3;
    float* sB   = sm + S_B;   float* sCur = sm + S_CUR; float* sA  = sm + S_A;
    float* sN0s = sm + S_N0S; float* sbD1 = sm + S_BD1; float* sbD2 = sm + S_BD2;
    float* sK2  = sm + S_K2;  float* sb2  = sm + S_B2;

    const int tid = threadIdx.x;
    const int wg  = blockIdx.x;
    const int j0  = wg * 4;     // h1 / n0 dims
    const int c0  = wg * 2;     // a / h2 dims

    // ---- startup: stage weight slices into LDS ----
    #pragma unroll
    for (int it = 0; it < 4; ++it) {
        int k = tid + it*256;
        float4 v;
        v = *(const float4*)&D1[(size_t)k*1024 + j0];        *(float4*)&sD1a[swz(k)*4] = v;
        v = *(const float4*)&D1[(size_t)(1024+k)*1024 + j0]; *(float4*)&sD1b[swz(k)*4] = v;
        v = *(const float4*)&D2[(size_t)k*1024 + j0];        *(float4*)&sD2[swz(k)*4]  = v;
        float2 w;
        w = *(const float2*)&W1[(size_t)k*512 + c0];         *(float2*)&sW1[swz(k)*2] = w;
        w = *(const float2*)&E[(size_t)k*512 + c0];          *(float2*)&sE[swz(k)*2]  = w;
    }
    #pragma unroll
    for (int it = 0; it < 8; ++it) {
        int f4 = tid + it*256;
        *(float4*)&sW2[f4*4] = *(const float4*)&W2[f4*4];
    }
    if (tid < 64) {
        int j = tid & 3, i = tid >> 2;
        sQ1[j*16+i] = Q1[i*1024 + j0 + j];
        sQ2[j*16+i] = Q2[i*1024 + j0 + j];
        sB [j*16+i] = Bm[i*1024 + j0 + j];
    }
    if (tid < 32) { int c = tid & 1, i = tid >> 1; sQ3[c*16+i] = Q3[i*512 + c0 + c]; }
    if (tid < 4)  { sbD1[tid] = bD1[j0+tid]; sbD2[tid] = bD2[j0+tid]; }
    if (tid < 2)  { sK2[tid] = K2v[c0+tid]; }
    if (tid < 16) { sb2[tid] = b2[tid]; }
    sC[tid] = 0.f;  // zero both coef buffers (c_{-1} = c_{-2} = 0)
    if (tid < 32) {
        int j = tid & 3, m = tid >> 2;
        float v  = x[((size_t)m*SEQ + (SEQ-1))*1024 + j0 + j];
        float v2 = x[((size_t)m*SEQ + (SEQ-2))*1024 + j0 + j];
        sN0s[j*8+m] = v;
        __hip_atomic_store(&N0g[m*1024 + j0 + j],        v,  __ATOMIC_RELAXED, __HIP_MEMORY_SCOPE_AGENT);
        __hip_atomic_store(&N0g[8192 + m*1024 + j0 + j], v2, __ATOMIC_RELAXED, __HIP_MEMORY_SCOPE_AGENT);
    }
    int bud = 3000000;
    gbar(ctr, 0, tid, bud);

    for (int t = 0; t <= TSTEPS; ++t) {
        const int p = t & 1;
        float* cCur  = &sC[p*128];        // c_{t-1}
        float* cPrev = &sC[(1-p)*128];    // c_{t-2}

        // ---- PHASE 1 ----
        if (t > 0) {
            // stage h2_{t-1} into LDS (padded rows)
            #pragma unroll
            for (int r2 = 0; r2 < 4; ++r2) {
                int f = r2*256 + tid;
                int m = f >> 7, kk = (f & 127) * 4;
                float4 v = *(const float4*)&H2g[m*512 + kk];
                *(float4*)&sH2[m*516 + kk] = v;
            }
            __syncthreads();
            // coefs c_{t-1} = h2 @ W2 + b2 (redundant per WG, split over threads)
            {
                int kh = tid >> 5, mm = (tid >> 2) & 7, ig = tid & 3;
                int k0 = kh * 64;
                float a0=0.f,a1=0.f,a2=0.f,a3=0.f;
                #pragma unroll
                for (int kk = 0; kk < 64; kk += 4) {
                    float4 h = *(float4*)&sH2[mm*516 + k0 + kk];
                    #pragma unroll
                    for (int q = 0; q < 4; ++q) {
                        float4 w = *(float4*)&sW2[(k0+kk+q)*16 + ig*4];
                        float hv = GETQ(h,q);
                        a0 = fmaf(hv,w.x,a0); a1 = fmaf(hv,w.y,a1);
                        a2 = fmaf(hv,w.z,a2); a3 = fmaf(hv,w.w,a3);
                    }
                }
                float* r = sRed + tid*13;
                r[0]=a0; r[1]=a1; r[2]=a2; r[3]=a3;
            }
            __syncthreads();
            if (tid < 128) {
                int mm = tid >> 4, i = tid & 15, ig = i >> 2, ii = i & 3;
                float s = sb2[i];
                #pragma unroll
                for (int kh = 0; kh < 8; ++kh) s += sRed[(kh*32 + mm*4 + ig)*13 + ii];
                cCur[mm*16 + i] = s;
            }
            __syncthreads();
        }
        // cur_t = n0_{t-1} + 0.1 * c_{t-1} @ B ; emit output row S+t-1
        if (tid < 32) {
            int j = tid & 3, m = tid >> 2;
            float s = sN0s[j*8+m];
            #pragma unroll
            for (int i = 0; i < 16; ++i) s = fmaf(0.1f * sB[j*16+i], cCur[m*16+i], s);
            sCur[j*8+m] = s;
            if (t > 0) outp[((size_t)m*4096 + SEQ + (t-1))*1024 + j0 + j] = s;
        }
        __syncthreads();
        if (t == TSTEPS) break;

        // h1 and a K-loops
        {
            const float* __restrict__ xv1 = N0g + p*8192;       // n0_{t-1}
            const float* __restrict__ xv2 = N0g + (1-p)*8192;   // n0_{t-2}
            const int mp = tid & 3, kr = tid >> 2;
            const int m0 = mp*2, kb = kr*16;
            float h00=0,h01=0,h10=0,h11=0,h20=0,h21=0,h30=0,h31=0;
            float a00=0,a01=0,a10=0,a11=0;
            #pragma unroll
            for (int bb = 0; bb < 4; ++bb) {
                const int k = kb + bb*4;
                const float4 x0 = *(const float4*)(xv1 + m0*1024 + k);
                const float4 x1 = *(const float4*)(xv1 + (m0+1)*1024 + k);
                #pragma unroll
                for (int q = 0; q < 4; ++q) {
                    const int ks = swz(k+q);
                    const float4 w  = *(const float4*)(sD1a + ks*4);
                    const float2 wa = *(const float2*)(sW1  + ks*2);
                    const float u0 = GETQ(x0,q), u1 = GETQ(x1,q);
                    h00=fmaf(w.x,u0,h00); h01=fmaf(w.x,u1,h01);
                    h10=fmaf(w.y,u0,h10); h11=fmaf(w.y,u1,h11);
                    h20=fmaf(w.z,u0,h20); h21=fmaf(w.z,u1,h21);
                    h30=fmaf(w.w,u0,h30); h31=fmaf(w.w,u1,h31);
                    a00=fmaf(wa.x,u0,a00); a01=fmaf(wa.x,u1,a01);
                    a10=fmaf(wa.y,u0,a10); a11=fmaf(wa.y,u1,a11);
                }
            }
            #pragma unroll
            for (int bb = 0; bb < 4; ++bb) {
                const int k = kb + bb*4;
                const float4 x0 = *(const float4*)(xv2 + m0*1024 + k);
                const float4 x1 = *(const float4*)(xv2 + (m0+1)*1024 + k);
                #pragma unroll
                for (int q = 0; q < 4; ++q) {
                    const int ks = swz(k+q);
                    const float4 w = *(const float4*)(sD1b + ks*4);
                    const float u0 = GETQ(x0,q), u1 = GETQ(x1,q);
                    h00=fmaf(w.x,u0,h00); h01=fmaf(w.x,u1,h01);
                    h10=fmaf(w.y,u0,h10); h11=fmaf(w.y,u1,h11);
                    h20=fmaf(w.z,u0,h20); h21=fmaf(w.z,u1,h21);
                    h30=fmaf(w.w,u0,h30); h31=fmaf(w.w,u1,h31);
                }
            }
            float* r = sRed + tid*13;
            r[0]=h00; r[1]=h01; r[2]=h10; r[3]=h11; r[4]=h20; r[5]=h21; r[6]=h30; r[7]=h31;
            r[8]=a00; r[9]=a01; r[10]=a10; r[11]=a11;
        }
        __syncthreads();
        if (tid < 32) {  // h1 reduce + tanh
            int j = tid & 3, m = tid >> 2, mp2 = m >> 1, ml = m & 1;
            float s0=0,s1=0,s2=0,s3=0;
            #pragma unroll
            for (int kr = 0; kr < 64; kr += 4) {
                s0 += sRed[((kr+0)*4+mp2)*13 + j*2 + ml];
                s1 += sRed[((kr+1)*4+mp2)*13 + j*2 + ml];
                s2 += sRed[((kr+2)*4+mp2)*13 + j*2 + ml];
                s3 += sRed[((kr+3)*4+mp2)*13 + j*2 + ml];
            }
            float s = sbD1[j] + (s0+s1) + (s2+s3);
            float qs = 0.f;
            #pragma unroll
            for (int i = 0; i < 16; ++i)
                qs += sQ1[j*16+i]*cCur[m*16+i] + sQ2[j*16+i]*cPrev[m*16+i];
            s = tanhf(s + 0.1f*qs);
            __hip_atomic_store(&H1g[m*1024 + j0 + j], s, __ATOMIC_RELAXED, __HIP_MEMORY_SCOPE_AGENT);
        } else if (tid < 48) {  // a reduce
            int r = tid - 32; int cc = r & 1, m = r >> 1, mp2 = m >> 1, ml = m & 1;
            float s0=0,s1=0;
            #pragma unroll
            for (int kr = 0; kr < 64; kr += 2) {
                s0 += sRed[((kr+0)*4+mp2)*13 + 8 + cc*2 + ml];
                s1 += sRed[((kr+1)*4+mp2)*13 + 8 + cc*2 + ml];
            }
            float s = sK2[cc] + s0 + s1;
            float qs = 0.f;
            #pragma unroll
            for (int i = 0; i < 16; ++i) qs += sQ3[cc*16+i]*cCur[m*16+i];
            sA[cc*8+m] = s + 0.1f*qs;
        }
        gbar(ctr, 1 + 2*t, tid, bud);

        // ---- PHASE 2 ----
        {
            const int mp = tid & 3, kr = tid >> 2;
            const int m0 = mp*2, kb = kr*16;
            float n00=0,n01=0,n10=0,n11=0,n20=0,n21=0,n30=0,n31=0;
            float z00=0,z01=0,z10=0,z11=0;
            #pragma unroll
            for (int bb = 0; bb < 4; ++bb) {
                const int k = kb + bb*4;
                const float4 x0 = *(const float4*)(H1g + m0*1024 + k);
                const float4 x1 = *(const float4*)(H1g + (m0+1)*1024 + k);
                #pragma unroll
                for (int q = 0; q < 4; ++q) {
                    const int ks = swz(k+q);
                    const float4 w  = *(const float4*)(sD2 + ks*4);
                    const float2 we = *(const float2*)(sE  + ks*2);
                    const float u0 = GETQ(x0,q), u1 = GETQ(x1,q);
                    n00=fmaf(w.x,u0,n00); n01=fmaf(w.x,u1,n01);
                    n10=fmaf(w.y,u0,n10); n11=fmaf(w.y,u1,n11);
                    n20=fmaf(w.z,u0,n20); n21=fmaf(w.z,u1,n21);
                    n30=fmaf(w.w,u0,n30); n31=fmaf(w.w,u1,n31);
                    z00=fmaf(we.x,u0,z00); z01=fmaf(we.x,u1,z01);
                    z10=fmaf(we.y,u0,z10); z11=fmaf(we.y,u1,z11);
                }
            }
            float* r = sRed + tid*13;
            r[0]=n00; r[1]=n01; r[2]=n10; r[3]=n11; r[4]=n20; r[5]=n21; r[6]=n30; r[7]=n31;
            r[8]=z00; r[9]=z01; r[10]=z10; r[11]=z11;
        }
        __syncthreads();
        if (tid < 32) {  // n0 reduce
            int j = tid & 3, m = tid >> 2, mp2 = m >> 1, ml = m & 1;
            float s0=0,s1=0,s2=0,s3=0;
            #pragma unroll
            for (int kr = 0; kr < 64; kr += 4) {
                s0 += sRed[((kr+0)*4+mp2)*13 + j*2 + ml];
                s1 += sRed[((kr+1)*4+mp2)*13 + j*2 + ml];
                s2 += sRed[((kr+2)*4+mp2)*13 + j*2 + ml];
                s3 += sRed[((kr+3)*4+mp2)*13 + j*2 + ml];
            }
            float s = sCur[j*8+m] + sbD2[j] + (s0+s1) + (s2+s3);
            __hip_atomic_store(&N0g[(1-p)*8192 + m*1024 + j0 + j], s, __ATOMIC_RELAXED, __HIP_MEMORY_SCOPE_AGENT);
            sN0s[j*8+m] = s;
        } else if (tid < 48) {  // h2 = gelu(a + h1@E)
            int r = tid - 32; int cc = r & 1, m = r >> 1, mp2 = m >> 1, ml = m & 1;
            float s0=0,s1=0;
            #pragma unroll
            for (int kr = 0; kr < 64; kr += 2) {
                s0 += sRed[((kr+0)*4+mp2)*13 + 8 + cc*2 + ml];
                s1 += sRed[((kr+1)*4+mp2)*13 + 8 + cc*2 + ml];
            }
            float s = sA[cc*8+m] + s0 + s1;
            float g = 0.5f * s * (1.0f + erff(s * 0.70710678118654752f));
            __hip_atomic_store(&H2g[m*512 + c0 + cc], g, __ATOMIC_RELAXED, __HIP_MEMORY_SCOPE_AGENT);
        }
        gbar(ctr, 2 + 2*t, tid, bud);
    }
}

// ---------------- host launcher ----------------
extern "C" void kernel_launch(void* const* d_in, const int* in_sizes, int n_in,
                              void* d_out, int out_size, void* d_ws, size_t ws_size,
                              hipStream_t stream) {
    const float* x   = (const float*)d_in[0];
    const float* Bm  = (const float*)d_in[1];
    const float* W1  = (const float*)d_in[2];
    const float* b1  = (const float*)d_in[3];
    const float* W2  = (const float*)d_in[4];
    const float* b2  = (const float*)d_in[5];
    const float* D1  = (const float*)d_in[6];
    const float* bD1 = (const float*)d_in[7];
    const float* D2  = (const float*)d_in[8];
    const float* bD2 = (const float*)d_in[9];
    float* out = (float*)d_out;
    float* ws  = (float*)d_ws;

    float* E   = ws + OFF_E;
    float* Q1  = ws + OFF_Q1;
    float* Q2  = ws + OFF_Q2;
    float* Q3  = ws + OFF_Q3;
    float* K2v = ws + OFF_K2;
    float* N0  = ws + OFF_N0;
    float* H1  = ws + OFF_H1;
    float* H2  = ws + OFF_H2;
    unsigned* ctr = (unsigned*)(ws + OFF_CTR);

    // zero barrier counters (monotonic per-phase counters)
    hipMemsetAsync(ctr, 0, 4097 * sizeof(unsigned), stream);

    // out[:, :2048, :] = x
    copy_x_kernel<<<4096, 256, 0, stream>>>((const float4*)x, (float4*)out);

    // precompute E, Q1, Q2, Q3, K2
    gemm_E_kernel<<<dim3(16, 8), 256, 0, stream>>>(D2, W1, E);
    qk_kernel<<<162, 256, 0, stream>>>(Bm, D1, W1, b1, bD2, Q1, Q2, Q3, K2v);

    // persistent recurrence kernel: 256 WGs (1/CU, forced by LDS usage)
    (void)hipFuncSetAttribute((const void*)main_kernel,
                              hipFuncAttributeMaxDynamicSharedMemorySize, SMEM_BYTES);
    main_kernel<<<NWG, TPB, SMEM_BYTES, stream>>>(
        x, Bm, W1, b1, W2, b2, D1, bD1, D2, bD2, out,
        E, Q1, Q2, Q3, K2v, N0, H1, H2, ctr);
}

// Round 4
// 76624.585 us; speedup vs baseline: 1.2691x; 1.2691x over previous
//
#include <hip/hip_runtime.h>
#include <cstddef>

// ---------------- problem constants ----------------
#define DIMD   1024
#define DIMH   512
#define NB     16
#define MB     8          // batch
#define SEQ    2048
#define TSTEPS 2048       // extrapolation steps
#define NWG    256
#define TPB    256

// ws layout (float offsets)
#define OFF_E   0          // 1024x512
#define OFF_Q1  524288     // 16x1024
#define OFF_Q2  540672     // 16x1024
#define OFF_Q3  557056     // 16x512
#define OFF_K2  565248     // 512
#define OFF_N0  565760     // 2 x 8 x 1024
#define OFF_H1  582144     // 8 x 1024
#define OFF_H2  590336     // 8 x 512
#define OFF_FLG 594432     // 256 flags x 16 u32 stride + release word
#define FLAG_STRIDE 16     // u32s = 64 B per flag line
#define WS_FLOATS (OFF_FLG + 4200)

// LDS layout (float offsets), total 32618 floats = 130472 bytes
#define S_D1A 0
#define S_D1B 4096
#define S_D2  8192
#define S_W1  12288
#define S_E   14336
#define S_W2  16384
#define S_H2  24576      // [8][516]
#define S_RED 28704      // [256][13]
#define S_C   32032      // [2][128]
#define S_Q1  32288      // [4][16]
#define S_Q2  32352
#define S_Q3  32416      // [2][16]
#define S_B   32448      // [4][16]
#define S_CUR 32512      // [4][8]
#define S_A   32544      // [2][8]
#define S_N0S 32560      // [4][8]
#define S_BD1 32592
#define S_BD2 32596
#define S_K2  32600
#define S_B2  32602
#define SMEM_FLOATS 32618
#define SMEM_BYTES  (SMEM_FLOATS*4)

__device__ __forceinline__ int swz(int k) { return k ^ ((k >> 4) & 7); }

#define GETQ(v,q) ((q)==0?(v).x:(q)==1?(v).y:(q)==2?(v).z:(v).w)

// ---------------- copy x into out[:, :2048, :] ----------------
__global__ __launch_bounds__(256) void copy_x_kernel(const float4* __restrict__ x,
                                                     float4* __restrict__ out) {
    const int total = MB * SEQ * (DIMD/4); // 4,194,304
    for (int i = blockIdx.x*256 + threadIdx.x; i < total; i += 4096*256) {
        int j = i & 255;
        int s = (i >> 8) & 2047;
        int m = i >> 19;
        out[((size_t)m*4096 + s)*256 + j] = x[i];
    }
}

// ---------------- E = D2 @ W1 (1024x512) ----------------
__global__ __launch_bounds__(256) void gemm_E_kernel(const float* __restrict__ A,
                                                     const float* __restrict__ Bw,
                                                     float* __restrict__ C) {
    __shared__ float As[64][17];
    __shared__ float Bs[16][65];
    const int r0 = blockIdx.x * 64, c0 = blockIdx.y * 64;
    const int tx = threadIdx.x & 15, ty = threadIdx.x >> 4;
    float acc[4][4] = {};
    for (int k0 = 0; k0 < 1024; k0 += 16) {
        {
            int row = threadIdx.x >> 2, c4 = (threadIdx.x & 3) * 4;
            float4 av = *(const float4*)&A[(size_t)(r0+row)*1024 + k0 + c4];
            As[row][c4+0]=av.x; As[row][c4+1]=av.y; As[row][c4+2]=av.z; As[row][c4+3]=av.w;
            int row2 = threadIdx.x >> 4, cc = (threadIdx.x & 15) * 4;
            float4 bv = *(const float4*)&Bw[(size_t)(k0+row2)*512 + c0 + cc];
            Bs[row2][cc+0]=bv.x; Bs[row2][cc+1]=bv.y; Bs[row2][cc+2]=bv.z; Bs[row2][cc+3]=bv.w;
        }
        __syncthreads();
        #pragma unroll
        for (int kk = 0; kk < 16; ++kk) {
            float av[4], bv[4];
            #pragma unroll
            for (int u=0;u<4;++u) av[u] = As[ty*4+u][kk];
            #pragma unroll
            for (int v=0;v<4;++v) bv[v] = Bs[kk][tx*4+v];
            #pragma unroll
            for (int u=0;u<4;++u)
                #pragma unroll
                for (int v=0;v<4;++v) acc[u][v] = fmaf(av[u], bv[v], acc[u][v]);
        }
        __syncthreads();
    }
    #pragma unroll
    for (int u=0;u<4;++u)
        #pragma unroll
        for (int v=0;v<4;++v)
            C[(size_t)(r0+ty*4+u)*512 + c0+tx*4+v] = acc[u][v];
}

// ---------------- Q1=B@D1a, Q2=B@D1b, Q3=B@W1, K2=b1+bD2@W1 ----------------
__global__ __launch_bounds__(256) void qk_kernel(const float* __restrict__ Bm,
                                                 const float* __restrict__ D1,
                                                 const float* __restrict__ W1,
                                                 const float* __restrict__ b1,
                                                 const float* __restrict__ bD2,
                                                 float* __restrict__ Q1, float* __restrict__ Q2,
                                                 float* __restrict__ Q3, float* __restrict__ K2) {
    int gid = blockIdx.x*256 + threadIdx.x;
    if (gid < 16384) {
        int i = gid >> 10, j = gid & 1023; float s = 0.f;
        for (int k = 0; k < 1024; ++k) s = fmaf(Bm[i*1024+k], D1[(size_t)k*1024 + j], s);
        Q1[gid] = s;
    } else if (gid < 32768) {
        int g = gid - 16384; int i = g >> 10, j = g & 1023; float s = 0.f;
        for (int k = 0; k < 1024; ++k) s = fmaf(Bm[i*1024+k], D1[(size_t)(1024+k)*1024 + j], s);
        Q2[g] = s;
    } else if (gid < 40960) {
        int g = gid - 32768; int i = g >> 9, c = g & 511; float s = 0.f;
        for (int k = 0; k < 1024; ++k) s = fmaf(Bm[i*1024+k], W1[(size_t)k*512 + c], s);
        Q3[g] = s;
    } else if (gid < 41472) {
        int c = gid - 40960; float s = b1[c];
        for (int k = 0; k < 1024; ++k) s = fmaf(bD2[k], W1[(size_t)k*512 + c], s);
        K2[c] = s;
    }
}

// ---------------- grid barrier: distributed flags + master aggregate ----------------
// Each WG stores epoch e to its own 64B flag line (no RMW, no contention).
// WG0's 256 threads poll the 256 flags in parallel, then publish `rel = e`.
// Other WGs poll `rel` read-only. Epochs are monotonic; no resets (replay-safe
// because the launcher memsets the flag region each call).
__device__ __forceinline__ void gbar(unsigned* flags, unsigned* rel, unsigned e,
                                     int wg, int tid, int& bud) {
    __builtin_amdgcn_fence(__ATOMIC_RELEASE, "agent");
    __syncthreads();
    if (wg == 0) {
        if (tid == 0)
            __hip_atomic_store(&flags[0], e, __ATOMIC_RELAXED, __HIP_MEMORY_SCOPE_AGENT);
        unsigned v;
        do {
            v = __hip_atomic_load(&flags[tid * FLAG_STRIDE], __ATOMIC_RELAXED,
                                  __HIP_MEMORY_SCOPE_AGENT);
        } while (v < e && --bud > 0);
        __syncthreads();
        if (tid == 0)
            __hip_atomic_store(rel, e, __ATOMIC_RELAXED, __HIP_MEMORY_SCOPE_AGENT);
    } else {
        if (tid == 0) {
            __hip_atomic_store(&flags[wg * FLAG_STRIDE], e, __ATOMIC_RELAXED,
                               __HIP_MEMORY_SCOPE_AGENT);
            unsigned v;
            do {
                v = __hip_atomic_load(rel, __ATOMIC_RELAXED, __HIP_MEMORY_SCOPE_AGENT);
            } while (v < e && --bud > 0);
        }
        __syncthreads();
    }
    __builtin_amdgcn_fence(__ATOMIC_ACQUIRE, "agent");
}

// ---------------- persistent main kernel ----------------
__global__ __launch_bounds__(256, 1) void main_kernel(
    const float* __restrict__ x, const float* __restrict__ Bm,
    const float* __restrict__ W1, const float* __restrict__ b1,
    const float* __restrict__ W2, const float* __restrict__ b2,
    const float* __restrict__ D1, const float* __restrict__ bD1,
    const float* __restrict__ D2, const float* __restrict__ bD2,
    float* __restrict__ outp,
    const float* __restrict__ E, const float* __restrict__ Q1,
    const float* __restrict__ Q2, const float* __restrict__ Q3,
    const float* __restrict__ K2v,
    float* __restrict__ N0g, float* __restrict__ H1g, float* __restrict__ H2g,
    unsigned* __restrict__ flags)
{
    extern __shared__ float sm[];
    float* sD1a = sm + S_D1A; float* sD1b = sm + S_D1B; float* sD2 = sm + S_D2;
    float* sW1  = sm + S_W1;  float* sE   = sm + S_E;   float* sW2 = sm + S_W2;
    float* sH2  = sm + S_H2;  float* sRed = sm + S_RED; float* sC  = sm + S_C;
    float* sQ1  = sm + S_Q1;  float* sQ2  = sm + S_Q2;  float* sQ3 = sm + S_Q3;
    float* sB   = sm + S_B;   float* sCur = sm + S_CUR; float* sA  = sm + S_A;
    float* sN0s = sm + S_N0S; float* sbD1 = sm + S_BD1; float* sbD2 = sm + S_BD2;
    float* sK2  = sm + S_K2;  float* sb2  = sm + S_B2;

    unsigned* rel = flags + NWG * FLAG_STRIDE;

    const int tid = threadIdx.x;
    const int wg  = blockIdx.x;
    const int j0  = wg * 4;     // h1 / n0 dims
    const int c0  = wg * 2;     // a / h2 dims

    // ---- startup: stage weight slices into LDS ----
    #pragma unroll
    for (int it = 0; it < 4; ++it) {
        int k = tid + it*256;
        float4 v;
        v = *(const float4*)&D1[(size_t)k*1024 + j0];        *(float4*)&sD1a[swz(k)*4] = v;
        v = *(const float4*)&D1[(size_t)(1024+k)*1024 + j0]; *(float4*)&sD1b[swz(k)*4] = v;
        v = *(const float4*)&D2[(size_t)k*1024 + j0];        *(float4*)&sD2[swz(k)*4]  = v;
        float2 w;
        w = *(const float2*)&W1[(size_t)k*512 + c0];         *(float2*)&sW1[swz(k)*2] = w;
        w = *(const float2*)&E[(size_t)k*512 + c0];          *(float2*)&sE[swz(k)*2]  = w;
    }
    #pragma unroll
    for (int it = 0; it < 8; ++it) {
        int f4 = tid + it*256;
        *(float4*)&sW2[f4*4] = *(const float4*)&W2[f4*4];
    }
    if (tid < 64) {
        int j = tid & 3, i = tid >> 2;
        sQ1[j*16+i] = Q1[i*1024 + j0 + j];
        sQ2[j*16+i] = Q2[i*1024 + j0 + j];
        sB [j*16+i] = Bm[i*1024 + j0 + j];
    }
    if (tid < 32) { int c = tid & 1, i = tid >> 1; sQ3[c*16+i] = Q3[i*512 + c0 + c]; }
    if (tid < 4)  { sbD1[tid] = bD1[j0+tid]; sbD2[tid] = bD2[j0+tid]; }
    if (tid < 2)  { sK2[tid] = K2v[c0+tid]; }
    if (tid < 16) { sb2[tid] = b2[tid]; }
    sC[tid] = 0.f;  // zero both coef buffers (c_{-1} = c_{-2} = 0)
    if (tid < 32) {
        int j = tid & 3, m = tid >> 2;
        float v  = x[((size_t)m*SEQ + (SEQ-1))*1024 + j0 + j];
        float v2 = x[((size_t)m*SEQ + (SEQ-2))*1024 + j0 + j];
        sN0s[j*8+m] = v;
        __hip_atomic_store(&N0g[m*1024 + j0 + j],        v,  __ATOMIC_RELAXED, __HIP_MEMORY_SCOPE_AGENT);
        __hip_atomic_store(&N0g[8192 + m*1024 + j0 + j], v2, __ATOMIC_RELAXED, __HIP_MEMORY_SCOPE_AGENT);
    }
    int bud = 3000000;
    unsigned ep = 1;
    gbar(flags, rel, ep++, wg, tid, bud);

    for (int t = 0; t <= TSTEPS; ++t) {
        const int p = t & 1;
        float* cCur  = &sC[p*128];        // c_{t-1}
        float* cPrev = &sC[(1-p)*128];    // c_{t-2}

        // ---- PHASE 1 ----
        if (t > 0) {
            // stage h2_{t-1} into LDS (padded rows)
            #pragma unroll
            for (int r2 = 0; r2 < 4; ++r2) {
                int f = r2*256 + tid;
                int m = f >> 7, kk = (f & 127) * 4;
                float4 v = *(const float4*)&H2g[m*512 + kk];
                *(float4*)&sH2[m*516 + kk] = v;
            }
            __syncthreads();
            // coefs c_{t-1} = h2 @ W2 + b2 (redundant per WG, split over threads)
            {
                int kh = tid >> 5, mm = (tid >> 2) & 7, ig = tid & 3;
                int k0 = kh * 64;
                float a0=0.f,a1=0.f,a2=0.f,a3=0.f;
                #pragma unroll
                for (int kk = 0; kk < 64; kk += 4) {
                    float4 h = *(float4*)&sH2[mm*516 + k0 + kk];
                    #pragma unroll
                    for (int q = 0; q < 4; ++q) {
                        float4 w = *(float4*)&sW2[(k0+kk+q)*16 + ig*4];
                        float hv = GETQ(h,q);
                        a0 = fmaf(hv,w.x,a0); a1 = fmaf(hv,w.y,a1);
                        a2 = fmaf(hv,w.z,a2); a3 = fmaf(hv,w.w,a3);
                    }
                }
                float* r = sRed + tid*13;
                r[0]=a0; r[1]=a1; r[2]=a2; r[3]=a3;
            }
            __syncthreads();
            if (tid < 128) {
                int mm = tid >> 4, i = tid & 15, ig = i >> 2, ii = i & 3;
                float s = sb2[i];
                #pragma unroll
                for (int kh = 0; kh < 8; ++kh) s += sRed[(kh*32 + mm*4 + ig)*13 + ii];
                cCur[mm*16 + i] = s;
            }
            __syncthreads();
        }
        // cur_t = n0_{t-1} + 0.1 * c_{t-1} @ B ; emit output row S+t-1
        if (tid < 32) {
            int j = tid & 3, m = tid >> 2;
            float s = sN0s[j*8+m];
            #pragma unroll
            for (int i = 0; i < 16; ++i) s = fmaf(0.1f * sB[j*16+i], cCur[m*16+i], s);
            sCur[j*8+m] = s;
            if (t > 0) outp[((size_t)m*4096 + SEQ + (t-1))*1024 + j0 + j] = s;
        }
        __syncthreads();
        if (t == TSTEPS) break;

        // h1 and a K-loops
        {
            const float* __restrict__ xv1 = N0g + p*8192;       // n0_{t-1}
            const float* __restrict__ xv2 = N0g + (1-p)*8192;   // n0_{t-2}
            const int mp = tid & 3, kr = tid >> 2;
            const int m0 = mp*2, kb = kr*16;
            float h00=0,h01=0,h10=0,h11=0,h20=0,h21=0,h30=0,h31=0;
            float a00=0,a01=0,a10=0,a11=0;
            #pragma unroll
            for (int bb = 0; bb < 4; ++bb) {
                const int k = kb + bb*4;
                const float4 x0 = *(const float4*)(xv1 + m0*1024 + k);
                const float4 x1 = *(const float4*)(xv1 + (m0+1)*1024 + k);
                #pragma unroll
                for (int q = 0; q < 4; ++q) {
                    const int ks = swz(k+q);
                    const float4 w  = *(const float4*)(sD1a + ks*4);
                    const float2 wa = *(const float2*)(sW1  + ks*2);
                    const float u0 = GETQ(x0,q), u1 = GETQ(x1,q);
                    h00=fmaf(w.x,u0,h00); h01=fmaf(w.x,u1,h01);
                    h10=fmaf(w.y,u0,h10); h11=fmaf(w.y,u1,h11);
                    h20=fmaf(w.z,u0,h20); h21=fmaf(w.z,u1,h21);
                    h30=fmaf(w.w,u0,h30); h31=fmaf(w.w,u1,h31);
                    a00=fmaf(wa.x,u0,a00); a01=fmaf(wa.x,u1,a01);
                    a10=fmaf(wa.y,u0,a10); a11=fmaf(wa.y,u1,a11);
                }
            }
            #pragma unroll
            for (int bb = 0; bb < 4; ++bb) {
                const int k = kb + bb*4;
                const float4 x0 = *(const float4*)(xv2 + m0*1024 + k);
                const float4 x1 = *(const float4*)(xv2 + (m0+1)*1024 + k);
                #pragma unroll
                for (int q = 0; q < 4; ++q) {
                    const int ks = swz(k+q);
                    const float4 w = *(const float4*)(sD1b + ks*4);
                    const float u0 = GETQ(x0,q), u1 = GETQ(x1,q);
                    h00=fmaf(w.x,u0,h00); h01=fmaf(w.x,u1,h01);
                    h10=fmaf(w.y,u0,h10); h11=fmaf(w.y,u1,h11);
                    h20=fmaf(w.z,u0,h20); h21=fmaf(w.z,u1,h21);
                    h30=fmaf(w.w,u0,h30); h31=fmaf(w.w,u1,h31);
                }
            }
            float* r = sRed + tid*13;
            r[0]=h00; r[1]=h01; r[2]=h10; r[3]=h11; r[4]=h20; r[5]=h21; r[6]=h30; r[7]=h31;
            r[8]=a00; r[9]=a01; r[10]=a10; r[11]=a11;
        }
        __syncthreads();
        if (tid < 32) {  // h1 reduce + tanh
            int j = tid & 3, m = tid >> 2, mp2 = m >> 1, ml = m & 1;
            float s0=0,s1=0,s2=0,s3=0;
            #pragma unroll
            for (int kr = 0; kr < 64; kr += 4) {
                s0 += sRed[((kr+0)*4+mp2)*13 + j*2 + ml];
                s1 += sRed[((kr+1)*4+mp2)*13 + j*2 + ml];
                s2 += sRed[((kr+2)*4+mp2)*13 + j*2 + ml];
                s3 += sRed[((kr+3)*4+mp2)*13 + j*2 + ml];
            }
            float s = sbD1[j] + (s0+s1) + (s2+s3);
            float qs = 0.f;
            #pragma unroll
            for (int i = 0; i < 16; ++i)
                qs += sQ1[j*16+i]*cCur[m*16+i] + sQ2[j*16+i]*cPrev[m*16+i];
            s = tanhf(s + 0.1f*qs);
            __hip_atomic_store(&H1g[m*1024 + j0 + j], s, __ATOMIC_RELAXED, __HIP_MEMORY_SCOPE_AGENT);
        } else if (tid < 48) {  // a reduce
            int r = tid - 32; int cc = r & 1, m = r >> 1, mp2 = m >> 1, ml = m & 1;
            float s0=0,s1=0;
            #pragma unroll
            for (int kr = 0; kr < 64; kr += 2) {
                s0 += sRed[((kr+0)*4+mp2)*13 + 8 + cc*2 + ml];
                s1 += sRed[((kr+1)*4+mp2)*13 + 8 + cc*2 + ml];
            }
            float s = sK2[cc] + s0 + s1;
            float qs = 0.f;
            #pragma unroll
            for (int i = 0; i < 16; ++i) qs += sQ3[cc*16+i]*cCur[m*16+i];
            sA[cc*8+m] = s + 0.1f*qs;
        }
        gbar(flags, rel, ep++, wg, tid, bud);

        // ---- PHASE 2 ----
        {
            const int mp = tid & 3, kr = tid >> 2;
            const int m0 = mp*2, kb = kr*16;
            float n00=0,n01=0,n10=0,n11=0,n20=0,n21=0,n30=0,n31=0;
            float z00=0,z01=0,z10=0,z11=0;
            #pragma unroll
            for (int bb = 0; bb < 4; ++bb) {
                const int k = kb + bb*4;
                const float4 x0 = *(const float4*)(H1g + m0*1024 + k);
                const float4 x1 = *(const float4*)(H1g + (m0+1)*1024 + k);
                #pragma unroll
                for (int q = 0; q < 4; ++q) {
                    const int ks = swz(k+q);
                    const float4 w  = *(const float4*)(sD2 + ks*4);
                    const float2 we = *(const float2*)(sE  + ks*2);
                    const float u0 = GETQ(x0,q), u1 = GETQ(x1,q);
                    n00=fmaf(w.x,u0,n00); n01=fmaf(w.x,u1,n01);
                    n10=fmaf(w.y,u0,n10); n11=fmaf(w.y,u1,n11);
                    n20=fmaf(w.z,u0,n20); n21=fmaf(w.z,u1,n21);
                    n30=fmaf(w.w,u0,n30); n31=fmaf(w.w,u1,n31);
                    z00=fmaf(we.x,u0,z00); z01=fmaf(we.x,u1,z01);
                    z10=fmaf(we.y,u0,z10); z11=fmaf(we.y,u1,z11);
                }
            }
            float* r = sRed + tid*13;
            r[0]=n00; r[1]=n01; r[2]=n10; r[3]=n11; r[4]=n20; r[5]=n21; r[6]=n30; r[7]=n31;
            r[8]=z00; r[9]=z01; r[10]=z10; r[11]=z11;
        }
        __syncthreads();
        if (tid < 32) {  // n0 reduce
            int j = tid & 3, m = tid >> 2, mp2 = m >> 1, ml = m & 1;
            float s0=0,s1=0,s2=0,s3=0;
            #pragma unroll
            for (int kr = 0; kr < 64; kr += 4) {
                s0 += sRed[((kr+0)*4+mp2)*13 + j*2 + ml];
                s1 += sRed[((kr+1)*4+mp2)*13 + j*2 + ml];
                s2 += sRed[((kr+2)*4+mp2)*13 + j*2 + ml];
                s3 += sRed[((kr+3)*4+mp2)*13 + j*2 + ml];
            }
            float s = sCur[j*8+m] + sbD2[j] + (s0+s1) + (s2+s3);
            __hip_atomic_store(&N0g[(1-p)*8192 + m*1024 + j0 + j], s, __ATOMIC_RELAXED, __HIP_MEMORY_SCOPE_AGENT);
            sN0s[j*8+m] = s;
        } else if (tid < 48) {  // h2 = gelu(a + h1@E)
            int r = tid - 32; int cc = r & 1, m = r >> 1, mp2 = m >> 1, ml = m & 1;
            float s0=0,s1=0;
            #pragma unroll
            for (int kr = 0; kr < 64; kr += 2) {
                s0 += sRed[((kr+0)*4+mp2)*13 + 8 + cc*2 + ml];
                s1 += sRed[((kr+1)*4+mp2)*13 + 8 + cc*2 + ml];
            }
            float s = sA[cc*8+m] + s0 + s1;
            float g = 0.5f * s * (1.0f + erff(s * 0.70710678118654752f));
            __hip_atomic_store(&H2g[m*512 + c0 + cc], g, __ATOMIC_RELAXED, __HIP_MEMORY_SCOPE_AGENT);
        }
        gbar(flags, rel, ep++, wg, tid, bud);
    }
}

// ---------------- host launcher ----------------
extern "C" void kernel_launch(void* const* d_in, const int* in_sizes, int n_in,
                              void* d_out, int out_size, void* d_ws, size_t ws_size,
                              hipStream_t stream) {
    const float* x   = (const float*)d_in[0];
    const float* Bm  = (const float*)d_in[1];
    const float* W1  = (const float*)d_in[2];
    const float* b1  = (const float*)d_in[3];
    const float* W2  = (const float*)d_in[4];
    const float* b2  = (const float*)d_in[5];
    const float* D1  = (const float*)d_in[6];
    const float* bD1 = (const float*)d_in[7];
    const float* D2  = (const float*)d_in[8];
    const float* bD2 = (const float*)d_in[9];
    float* out = (float*)d_out;
    float* ws  = (float*)d_ws;

    float* E   = ws + OFF_E;
    float* Q1  = ws + OFF_Q1;
    float* Q2  = ws + OFF_Q2;
    float* Q3  = ws + OFF_Q3;
    float* K2v = ws + OFF_K2;
    float* N0  = ws + OFF_N0;
    float* H1  = ws + OFF_H1;
    float* H2  = ws + OFF_H2;
    unsigned* flags = (unsigned*)(ws + OFF_FLG);

    // zero flag lines + release word (epochs are monotonic within one launch)
    hipMemsetAsync(flags, 0, (NWG * FLAG_STRIDE + 16) * sizeof(unsigned), stream);

    // out[:, :2048, :] = x
    copy_x_kernel<<<4096, 256, 0, stream>>>((const float4*)x, (float4*)out);

    // precompute E, Q1, Q2, Q3, K2
    gemm_E_kernel<<<dim3(16, 8), 256, 0, stream>>>(D2, W1, E);
    qk_kernel<<<162, 256, 0, stream>>>(Bm, D1, W1, b1, bD2, Q1, Q2, Q3, K2v);

    // persistent recurrence kernel: 256 WGs (1/CU, forced by LDS usage)
    (void)hipFuncSetAttribute((const void*)main_kernel,
                              hipFuncAttributeMaxDynamicSharedMemorySize, SMEM_BYTES);
    main_kernel<<<NWG, TPB, SMEM_BYTES, stream>>>(
        x, Bm, W1, b1, W2, b2, D1, bD1, D2, bD2, out,
        E, Q1, Q2, Q3, K2v, N0, H1, H2, flags);
}

// Round 6
// 52136.249 us; speedup vs baseline: 1.8652x; 1.4697x over previous
//
#include <hip/hip_runtime.h>
#include <cstddef>

// ---------------- problem constants ----------------
#define DIMD   1024
#define DIMH   512
#define NB     16
#define MB     8          // batch
#define SEQ    2048
#define TSTEPS 2048       // extrapolation steps
#define NWG    256
#define TPB    256

// ws layout (float offsets)
#define OFF_E   0          // 1024x512
#define OFF_Q1  524288     // 16x1024
#define OFF_Q2  540672     // 16x1024
#define OFF_Q3  557056     // 16x512
#define OFF_K2  565248     // 512
#define OFF_N0  565760     // 2 x 8 x 1024
#define OFF_H1  582144     // 8 x 1024
#define OFF_H2  590336     // 8 x 512
#define OFF_FLG 594432     // 256 flags x 16 u32 stride + release word
#define FLAG_STRIDE 16     // u32s = 64 B per flag line
#define WS_FLOATS (OFF_FLG + 4200)

// LDS layout (float offsets), total 32618 floats = 130472 bytes
#define S_D1A 0
#define S_D1B 4096
#define S_D2  8192
#define S_W1  12288
#define S_E   14336
#define S_W2  16384
#define S_H2  24576      // [8][516]
#define S_RED 28704      // [256][13]
#define S_C   32032      // [2][128]
#define S_Q1  32288      // [4][16]
#define S_Q2  32352
#define S_Q3  32416      // [2][16]
#define S_B   32448      // [4][16]
#define S_CUR 32512      // [4][8]
#define S_A   32544      // [2][8]
#define S_N0S 32560      // [4][8]
#define S_BD1 32592
#define S_BD2 32596
#define S_K2  32600
#define S_B2  32602
#define SMEM_FLOATS 32618
#define SMEM_BYTES  (SMEM_FLOATS*4)

__device__ __forceinline__ int swz(int k) { return k ^ ((k >> 4) & 7); }

#define GETQ(v,q) ((q)==0?(v).x:(q)==1?(v).y:(q)==2?(v).z:(v).w)

typedef __attribute__((ext_vector_type(4))) float f32x4;

// L2-bypassing (sc0 sc1) 16B global load: coherent at the memory-side
// Infinity Cache without any buffer_inv. Result NOT ready until a
// subsequent s_waitcnt that ties the register (see WAITV macros).
#define LDSC(dst, addr) \
    asm volatile("global_load_dwordx4 %0, %1, off sc0 sc1" \
                 : "=v"(dst) : "v"(addr) : "memory")

// ---------------- copy x into out[:, :2048, :] ----------------
__global__ __launch_bounds__(256) void copy_x_kernel(const float4* __restrict__ x,
                                                     float4* __restrict__ out) {
    const int total = MB * SEQ * (DIMD/4); // 4,194,304
    for (int i = blockIdx.x*256 + threadIdx.x; i < total; i += 4096*256) {
        int j = i & 255;
        int s = (i >> 8) & 2047;
        int m = i >> 19;
        out[((size_t)m*4096 + s)*256 + j] = x[i];
    }
}

// ---------------- E = D2 @ W1 (1024x512) ----------------
__global__ __launch_bounds__(256) void gemm_E_kernel(const float* __restrict__ A,
                                                     const float* __restrict__ Bw,
                                                     float* __restrict__ C) {
    __shared__ float As[64][17];
    __shared__ float Bs[16][65];
    const int r0 = blockIdx.x * 64, c0 = blockIdx.y * 64;
    const int tx = threadIdx.x & 15, ty = threadIdx.x >> 4;
    float acc[4][4] = {};
    for (int k0 = 0; k0 < 1024; k0 += 16) {
        {
            int row = threadIdx.x >> 2, c4 = (threadIdx.x & 3) * 4;
            float4 av = *(const float4*)&A[(size_t)(r0+row)*1024 + k0 + c4];
            As[row][c4+0]=av.x; As[row][c4+1]=av.y; As[row][c4+2]=av.z; As[row][c4+3]=av.w;
            int row2 = threadIdx.x >> 4, cc = (threadIdx.x & 15) * 4;
            float4 bv = *(const float4*)&Bw[(size_t)(k0+row2)*512 + c0 + cc];
            Bs[row2][cc+0]=bv.x; Bs[row2][cc+1]=bv.y; Bs[row2][cc+2]=bv.z; Bs[row2][cc+3]=bv.w;
        }
        __syncthreads();
        #pragma unroll
        for (int kk = 0; kk < 16; ++kk) {
            float av[4], bv[4];
            #pragma unroll
            for (int u=0;u<4;++u) av[u] = As[ty*4+u][kk];
            #pragma unroll
            for (int v=0;v<4;++v) bv[v] = Bs[kk][tx*4+v];
            #pragma unroll
            for (int u=0;u<4;++u)
                #pragma unroll
                for (int v=0;v<4;++v) acc[u][v] = fmaf(av[u], bv[v], acc[u][v]);
        }
        __syncthreads();
    }
    #pragma unroll
    for (int u=0;u<4;++u)
        #pragma unroll
        for (int v=0;v<4;++v)
            C[(size_t)(r0+ty*4+u)*512 + c0+tx*4+v] = acc[u][v];
}

// ---------------- Q1=B@D1a, Q2=B@D1b, Q3=B@W1, K2=b1+bD2@W1 ----------------
__global__ __launch_bounds__(256) void qk_kernel(const float* __restrict__ Bm,
                                                 const float* __restrict__ D1,
                                                 const float* __restrict__ W1,
                                                 const float* __restrict__ b1,
                                                 const float* __restrict__ bD2,
                                                 float* __restrict__ Q1, float* __restrict__ Q2,
                                                 float* __restrict__ Q3, float* __restrict__ K2) {
    int gid = blockIdx.x*256 + threadIdx.x;
    if (gid < 16384) {
        int i = gid >> 10, j = gid & 1023; float s = 0.f;
        for (int k = 0; k < 1024; ++k) s = fmaf(Bm[i*1024+k], D1[(size_t)k*1024 + j], s);
        Q1[gid] = s;
    } else if (gid < 32768) {
        int g = gid - 16384; int i = g >> 10, j = g & 1023; float s = 0.f;
        for (int k = 0; k < 1024; ++k) s = fmaf(Bm[i*1024+k], D1[(size_t)(1024+k)*1024 + j], s);
        Q2[g] = s;
    } else if (gid < 40960) {
        int g = gid - 32768; int i = g >> 9, c = g & 511; float s = 0.f;
        for (int k = 0; k < 1024; ++k) s = fmaf(Bm[i*1024+k], W1[(size_t)k*512 + c], s);
        Q3[g] = s;
    } else if (gid < 41472) {
        int c = gid - 40960; float s = b1[c];
        for (int k = 0; k < 1024; ++k) s = fmaf(bD2[k], W1[(size_t)k*512 + c], s);
        K2[c] = s;
    }
}

// ---------------- grid barrier: distributed flags, NO cache maintenance ----
// Release fence = s_waitcnt only (agent scope). No acquire fence: all
// cross-WG data reads are sc0sc1 (L2-bypass) loads that meet the sc1
// write-through stores at the memory-side cache.
__device__ __forceinline__ void gbar(unsigned* flags, unsigned* rel, unsigned e,
                                     int wg, int tid, int& bud) {
    __builtin_amdgcn_fence(__ATOMIC_RELEASE, "agent");
    __syncthreads();
    if (wg == 0) {
        if (tid == 0)
            __hip_atomic_store(&flags[0], e, __ATOMIC_RELAXED, __HIP_MEMORY_SCOPE_AGENT);
        unsigned v;
        do {
            v = __hip_atomic_load(&flags[tid * FLAG_STRIDE], __ATOMIC_RELAXED,
                                  __HIP_MEMORY_SCOPE_AGENT);
        } while (v < e && --bud > 0);
        __syncthreads();
        if (tid == 0)
            __hip_atomic_store(rel, e, __ATOMIC_RELAXED, __HIP_MEMORY_SCOPE_AGENT);
    } else {
        if (tid == 0) {
            __hip_atomic_store(&flags[wg * FLAG_STRIDE], e, __ATOMIC_RELAXED,
                               __HIP_MEMORY_SCOPE_AGENT);
            unsigned v;
            do {
                v = __hip_atomic_load(rel, __ATOMIC_RELAXED, __HIP_MEMORY_SCOPE_AGENT);
            } while (v < e && --bud > 0);
        }
        __syncthreads();
    }
    asm volatile("" ::: "memory");
}

// ---------------- persistent main kernel ----------------
__global__ __launch_bounds__(256, 1) void main_kernel(
    const float* __restrict__ x, const float* __restrict__ Bm,
    const float* __restrict__ W1, const float* __restrict__ b1,
    const float* __restrict__ W2, const float* __restrict__ b2,
    const float* __restrict__ D1, const float* __restrict__ bD1,
    const float* __restrict__ D2, const float* __restrict__ bD2,
    float* __restrict__ outp,
    const float* __restrict__ E, const float* __restrict__ Q1,
    const float* __restrict__ Q2, const float* __restrict__ Q3,
    const float* __restrict__ K2v,
    float* __restrict__ N0g, float* __restrict__ H1g, float* __restrict__ H2g,
    unsigned* __restrict__ flags)
{
    extern __shared__ float sm[];
    float* sD1a = sm + S_D1A; float* sD1b = sm + S_D1B; float* sD2 = sm + S_D2;
    float* sW1  = sm + S_W1;  float* sE   = sm + S_E;   float* sW2 = sm + S_W2;
    float* sH2  = sm + S_H2;  float* sRed = sm + S_RED; float* sC  = sm + S_C;
    float* sQ1  = sm + S_Q1;  float* sQ2  = sm + S_Q2;  float* sQ3 = sm + S_Q3;
    float* sB   = sm + S_B;   float* sCur = sm + S_CUR; float* sA  = sm + S_A;
    float* sN0s = sm + S_N0S; float* sbD1 = sm + S_BD1; float* sbD2 = sm + S_BD2;
    float* sK2  = sm + S_K2;  float* sb2  = sm + S_B2;

    unsigned* rel = flags + NWG * FLAG_STRIDE;

    const int tid = threadIdx.x;
    const int wg  = blockIdx.x;
    const int j0  = wg * 4;     // h1 / n0 dims
    const int c0  = wg * 2;     // a / h2 dims

    // ---- startup: stage weight slices into LDS ----
    #pragma unroll
    for (int it = 0; it < 4; ++it) {
        int k = tid + it*256;
        float4 v;
        v = *(const float4*)&D1[(size_t)k*1024 + j0];        *(float4*)&sD1a[swz(k)*4] = v;
        v = *(const float4*)&D1[(size_t)(1024+k)*1024 + j0]; *(float4*)&sD1b[swz(k)*4] = v;
        v = *(const float4*)&D2[(size_t)k*1024 + j0];        *(float4*)&sD2[swz(k)*4]  = v;
        float2 w;
        w = *(const float2*)&W1[(size_t)k*512 + c0];         *(float2*)&sW1[swz(k)*2] = w;
        w = *(const float2*)&E[(size_t)k*512 + c0];          *(float2*)&sE[swz(k)*2]  = w;
    }
    #pragma unroll
    for (int it = 0; it < 8; ++it) {
        int f4 = tid + it*256;
        *(float4*)&sW2[f4*4] = *(const float4*)&W2[f4*4];
    }
    if (tid < 64) {
        int j = tid & 3, i = tid >> 2;
        sQ1[j*16+i] = Q1[i*1024 + j0 + j];
        sQ2[j*16+i] = Q2[i*1024 + j0 + j];
        sB [j*16+i] = Bm[i*1024 + j0 + j];
    }
    if (tid < 32) { int c = tid & 1, i = tid >> 1; sQ3[c*16+i] = Q3[i*512 + c0 + c]; }
    if (tid < 4)  { sbD1[tid] = bD1[j0+tid]; sbD2[tid] = bD2[j0+tid]; }
    if (tid < 2)  { sK2[tid] = K2v[c0+tid]; }
    if (tid < 16) { sb2[tid] = b2[tid]; }
    sC[tid] = 0.f;  // zero both coef buffers (c_{-1} = c_{-2} = 0)
    if (tid < 32) {
        int j = tid & 3, m = tid >> 2;
        float v  = x[((size_t)m*SEQ + (SEQ-1))*1024 + j0 + j];
        float v2 = x[((size_t)m*SEQ + (SEQ-2))*1024 + j0 + j];
        sN0s[j*8+m] = v;
        __hip_atomic_store(&N0g[m*1024 + j0 + j],        v,  __ATOMIC_RELAXED, __HIP_MEMORY_SCOPE_AGENT);
        __hip_atomic_store(&N0g[8192 + m*1024 + j0 + j], v2, __ATOMIC_RELAXED, __HIP_MEMORY_SCOPE_AGENT);
    }
    int bud = 3000000;
    unsigned ep = 1;
    gbar(flags, rel, ep++, wg, tid, bud);

    for (int t = 0; t <= TSTEPS; ++t) {
        const int p = t & 1;
        float* cCur  = &sC[p*128];        // c_{t-1}
        float* cPrev = &sC[(1-p)*128];    // c_{t-2}

        // ---- PHASE 1 ----
        if (t > 0) {
            // stage h2_{t-1} into LDS (padded rows) via sc loads
            {
                f32x4 g0, g1, g2, g3;
                const int f0 = tid, f1 = 256+tid, f2 = 512+tid, f3 = 768+tid;
                LDSC(g0, (const f32x4*)(H2g + (f0>>7)*512 + (f0&127)*4));
                LDSC(g1, (const f32x4*)(H2g + (f1>>7)*512 + (f1&127)*4));
                LDSC(g2, (const f32x4*)(H2g + (f2>>7)*512 + (f2&127)*4));
                LDSC(g3, (const f32x4*)(H2g + (f3>>7)*512 + (f3&127)*4));
                asm volatile("s_waitcnt vmcnt(0)"
                             : "+v"(g0), "+v"(g1), "+v"(g2), "+v"(g3) :: "memory");
                *(f32x4*)&sH2[(f0>>7)*516 + (f0&127)*4] = g0;
                *(f32x4*)&sH2[(f1>>7)*516 + (f1&127)*4] = g1;
                *(f32x4*)&sH2[(f2>>7)*516 + (f2&127)*4] = g2;
                *(f32x4*)&sH2[(f3>>7)*516 + (f3&127)*4] = g3;
            }
            __syncthreads();
            // coefs c_{t-1} = h2 @ W2 + b2 (redundant per WG, split over threads)
            {
                int kh = tid >> 5, mm = (tid >> 2) & 7, ig = tid & 3;
                int k0 = kh * 64;
                float a0=0.f,a1=0.f,a2=0.f,a3=0.f;
                #pragma unroll
                for (int kk = 0; kk < 64; kk += 4) {
                    float4 h = *(float4*)&sH2[mm*516 + k0 + kk];
                    #pragma unroll
                    for (int q = 0; q < 4; ++q) {
                        float4 w = *(float4*)&sW2[(k0+kk+q)*16 + ig*4];
                        float hv = GETQ(h,q);
                        a0 = fmaf(hv,w.x,a0); a1 = fmaf(hv,w.y,a1);
                        a2 = fmaf(hv,w.z,a2); a3 = fmaf(hv,w.w,a3);
                    }
                }
                float* r = sRed + tid*13;
                r[0]=a0; r[1]=a1; r[2]=a2; r[3]=a3;
            }
            __syncthreads();
            if (tid < 128) {
                int mm = tid >> 4, i = tid & 15, ig = i >> 2, ii = i & 3;
                float s = sb2[i];
                #pragma unroll
                for (int kh = 0; kh < 8; ++kh) s += sRed[(kh*32 + mm*4 + ig)*13 + ii];
                cCur[mm*16 + i] = s;
            }
            __syncthreads();
        }
        // cur_t = n0_{t-1} + 0.1 * c_{t-1} @ B ; emit output row S+t-1
        if (tid < 32) {
            int j = tid & 3, m = tid >> 2;
            float s = sN0s[j*8+m];
            #pragma unroll
            for (int i = 0; i < 16; ++i) s = fmaf(0.1f * sB[j*16+i], cCur[m*16+i], s);
            sCur[j*8+m] = s;
            if (t > 0) outp[((size_t)m*4096 + SEQ + (t-1))*1024 + j0 + j] = s;
        }
        __syncthreads();
        if (t == TSTEPS) break;

        // h1 and a K-loops (sc loads of n0_{t-1}, n0_{t-2})
        {
            const float* xv1 = N0g + p*8192;       // n0_{t-1}
            const float* xv2 = N0g + (1-p)*8192;   // n0_{t-2}
            const int mp = tid & 3, kr = tid >> 2;
            const int m0 = mp*2, kb = kr*16;
            const f32x4* pa0 = (const f32x4*)(xv1 + m0*1024 + kb);
            const f32x4* pa1 = (const f32x4*)(xv1 + (m0+1)*1024 + kb);
            const f32x4* pb0 = (const f32x4*)(xv2 + m0*1024 + kb);
            const f32x4* pb1 = (const f32x4*)(xv2 + (m0+1)*1024 + kb);
            f32x4 A0,A1,A2,A3,A4,A5,A6,A7, B0,B1,B2,B3,B4,B5,B6,B7;
            LDSC(A0, pa0+0); LDSC(A1, pa0+1); LDSC(A2, pa0+2); LDSC(A3, pa0+3);
            LDSC(A4, pa1+0); LDSC(A5, pa1+1); LDSC(A6, pa1+2); LDSC(A7, pa1+3);
            LDSC(B0, pb0+0); LDSC(B1, pb0+1); LDSC(B2, pb0+2); LDSC(B3, pb0+3);
            LDSC(B4, pb1+0); LDSC(B5, pb1+1); LDSC(B6, pb1+2); LDSC(B7, pb1+3);
            asm volatile("s_waitcnt vmcnt(0)"
                         : "+v"(A0),"+v"(A1),"+v"(A2),"+v"(A3),
                           "+v"(A4),"+v"(A5),"+v"(A6),"+v"(A7),
                           "+v"(B0),"+v"(B1),"+v"(B2),"+v"(B3),
                           "+v"(B4),"+v"(B5),"+v"(B6),"+v"(B7) :: "memory");
            float h00=0,h01=0,h10=0,h11=0,h20=0,h21=0,h30=0,h31=0;
            float a00=0,a01=0,a10=0,a11=0;
            #define FMA_P1A(x0v,x1v,bb) \
                _Pragma("unroll") \
                for (int q = 0; q < 4; ++q) { \
                    const int ks = swz(kb + (bb)*4 + q); \
                    const float4 w  = *(const float4*)(sD1a + ks*4); \
                    const float2 wa = *(const float2*)(sW1  + ks*2); \
                    const float u0 = GETQ(x0v,q), u1 = GETQ(x1v,q); \
                    h00=fmaf(w.x,u0,h00); h01=fmaf(w.x,u1,h01); \
                    h10=fmaf(w.y,u0,h10); h11=fmaf(w.y,u1,h11); \
                    h20=fmaf(w.z,u0,h20); h21=fmaf(w.z,u1,h21); \
                    h30=fmaf(w.w,u0,h30); h31=fmaf(w.w,u1,h31); \
                    a00=fmaf(wa.x,u0,a00); a01=fmaf(wa.x,u1,a01); \
                    a10=fmaf(wa.y,u0,a10); a11=fmaf(wa.y,u1,a11); \
                }
            FMA_P1A(A0,A4,0) FMA_P1A(A1,A5,1) FMA_P1A(A2,A6,2) FMA_P1A(A3,A7,3)
            #define FMA_P1B(x0v,x1v,bb) \
                _Pragma("unroll") \
                for (int q = 0; q < 4; ++q) { \
                    const int ks = swz(kb + (bb)*4 + q); \
                    const float4 w = *(const float4*)(sD1b + ks*4); \
                    const float u0 = GETQ(x0v,q), u1 = GETQ(x1v,q); \
                    h00=fmaf(w.x,u0,h00); h01=fmaf(w.x,u1,h01); \
                    h10=fmaf(w.y,u0,h10); h11=fmaf(w.y,u1,h11); \
                    h20=fmaf(w.z,u0,h20); h21=fmaf(w.z,u1,h21); \
                    h30=fmaf(w.w,u0,h30); h31=fmaf(w.w,u1,h31); \
                }
            FMA_P1B(B0,B4,0) FMA_P1B(B1,B5,1) FMA_P1B(B2,B6,2) FMA_P1B(B3,B7,3)
            float* r = sRed + tid*13;
            r[0]=h00; r[1]=h01; r[2]=h10; r[3]=h11; r[4]=h20; r[5]=h21; r[6]=h30; r[7]=h31;
            r[8]=a00; r[9]=a01; r[10]=a10; r[11]=a11;
        }
        __syncthreads();
        if (tid < 32) {  // h1 reduce + tanh
            int j = tid & 3, m = tid >> 2, mp2 = m >> 1, ml = m & 1;
            float s0=0,s1=0,s2=0,s3=0;
            #pragma unroll
            for (int kr = 0; kr < 64; kr += 4) {
                s0 += sRed[((kr+0)*4+mp2)*13 + j*2 + ml];
                s1 += sRed[((kr+1)*4+mp2)*13 + j*2 + ml];
                s2 += sRed[((kr+2)*4+mp2)*13 + j*2 + ml];
                s3 += sRed[((kr+3)*4+mp2)*13 + j*2 + ml];
            }
            float s = sbD1[j] + (s0+s1) + (s2+s3);
            float qs = 0.f;
            #pragma unroll
            for (int i = 0; i < 16; ++i)
                qs += sQ1[j*16+i]*cCur[m*16+i] + sQ2[j*16+i]*cPrev[m*16+i];
            s = tanhf(s + 0.1f*qs);
            __hip_atomic_store(&H1g[m*1024 + j0 + j], s, __ATOMIC_RELAXED, __HIP_MEMORY_SCOPE_AGENT);
        } else if (tid < 48) {  // a reduce
            int r = tid - 32; int cc = r & 1, m = r >> 1, mp2 = m >> 1, ml = m & 1;
            float s0=0,s1=0;
            #pragma unroll
            for (int kr = 0; kr < 64; kr += 2) {
                s0 += sRed[((kr+0)*4+mp2)*13 + 8 + cc*2 + ml];
                s1 += sRed[((kr+1)*4+mp2)*13 + 8 + cc*2 + ml];
            }
            float s = sK2[cc] + s0 + s1;
            float qs = 0.f;
            #pragma unroll
            for (int i = 0; i < 16; ++i) qs += sQ3[cc*16+i]*cCur[m*16+i];
            sA[cc*8+m] = s + 0.1f*qs;
        }
        gbar(flags, rel, ep++, wg, tid, bud);

        // ---- PHASE 2 ---- (sc loads of h1)
        {
            const int mp = tid & 3, kr = tid >> 2;
            const int m0 = mp*2, kb = kr*16;
            const f32x4* pa0 = (const f32x4*)(H1g + m0*1024 + kb);
            const f32x4* pa1 = (const f32x4*)(H1g + (m0+1)*1024 + kb);
            f32x4 A0,A1,A2,A3,A4,A5,A6,A7;
            LDSC(A0, pa0+0); LDSC(A1, pa0+1); LDSC(A2, pa0+2); LDSC(A3, pa0+3);
            LDSC(A4, pa1+0); LDSC(A5, pa1+1); LDSC(A6, pa1+2); LDSC(A7, pa1+3);
            asm volatile("s_waitcnt vmcnt(0)"
                         : "+v"(A0),"+v"(A1),"+v"(A2),"+v"(A3),
                           "+v"(A4),"+v"(A5),"+v"(A6),"+v"(A7) :: "memory");
            float n00=0,n01=0,n10=0,n11=0,n20=0,n21=0,n30=0,n31=0;
            float z00=0,z01=0,z10=0,z11=0;
            #define FMA_P2(x0v,x1v,bb) \
                _Pragma("unroll") \
                for (int q = 0; q < 4; ++q) { \
                    const int ks = swz(kb + (bb)*4 + q); \
                    const float4 w  = *(const float4*)(sD2 + ks*4); \
                    const float2 we = *(const float2*)(sE  + ks*2); \
                    const float u0 = GETQ(x0v,q), u1 = GETQ(x1v,q); \
                    n00=fmaf(w.x,u0,n00); n01=fmaf(w.x,u1,n01); \
                    n10=fmaf(w.y,u0,n10); n11=fmaf(w.y,u1,n11); \
                    n20=fmaf(w.z,u0,n20); n21=fmaf(w.z,u1,n21); \
                    n30=fmaf(w.w,u0,n30); n31=fmaf(w.w,u1,n31); \
                    z00=fmaf(we.x,u0,z00); z01=fmaf(we.x,u1,z01); \
                    z10=fmaf(we.y,u0,z10); z11=fmaf(we.y,u1,z11); \
                }
            FMA_P2(A0,A4,0) FMA_P2(A1,A5,1) FMA_P2(A2,A6,2) FMA_P2(A3,A7,3)
            float* r = sRed + tid*13;
            r[0]=n00; r[1]=n01; r[2]=n10; r[3]=n11; r[4]=n20; r[5]=n21; r[6]=n30; r[7]=n31;
            r[8]=z00; r[9]=z01; r[10]=z10; r[11]=z11;
        }
        __syncthreads();
        if (tid < 32) {  // n0 reduce
            int j = tid & 3, m = tid >> 2, mp2 = m >> 1, ml = m & 1;
            float s0=0,s1=0,s2=0,s3=0;
            #pragma unroll
            for (int kr = 0; kr < 64; kr += 4) {
                s0 += sRed[((kr+0)*4+mp2)*13 + j*2 + ml];
                s1 += sRed[((kr+1)*4+mp2)*13 + j*2 + ml];
                s2 += sRed[((kr+2)*4+mp2)*13 + j*2 + ml];
                s3 += sRed[((kr+3)*4+mp2)*13 + j*2 + ml];
            }
            float s = sCur[j*8+m] + sbD2[j] + (s0+s1) + (s2+s3);
            __hip_atomic_store(&N0g[(1-p)*8192 + m*1024 + j0 + j], s, __ATOMIC_RELAXED, __HIP_MEMORY_SCOPE_AGENT);
            sN0s[j*8+m] = s;
        } else if (tid < 48) {  // h2 = gelu(a + h1@E)
            int r = tid - 32; int cc = r & 1, m = r >> 1, mp2 = m >> 1, ml = m & 1;
            float s0=0,s1=0;
            #pragma unroll
            for (int kr = 0; kr < 64; kr += 2) {
                s0 += sRed[((kr+0)*4+mp2)*13 + 8 + cc*2 + ml];
                s1 += sRed[((kr+1)*4+mp2)*13 + 8 + cc*2 + ml];
            }
            float s = sA[cc*8+m] + s0 + s1;
            float g = 0.5f * s * (1.0f + erff(s * 0.70710678118654752f));
            __hip_atomic_store(&H2g[m*512 + c0 + cc], g, __ATOMIC_RELAXED, __HIP_MEMORY_SCOPE_AGENT);
        }
        gbar(flags, rel, ep++, wg, tid, bud);
    }
}

// ---------------- host launcher ----------------
extern "C" void kernel_launch(void* const* d_in, const int* in_sizes, int n_in,
                              void* d_out, int out_size, void* d_ws, size_t ws_size,
                              hipStream_t stream) {
    const float* x   = (const float*)d_in[0];
    const float* Bm  = (const float*)d_in[1];
    const float* W1  = (const float*)d_in[2];
    const float* b1  = (const float*)d_in[3];
    const float* W2  = (const float*)d_in[4];
    const float* b2  = (const float*)d_in[5];
    const float* D1  = (const float*)d_in[6];
    const float* bD1 = (const float*)d_in[7];
    const float* D2  = (const float*)d_in[8];
    const float* bD2 = (const float*)d_in[9];
    float* out = (float*)d_out;
    float* ws  = (float*)d_ws;

    float* E   = ws + OFF_E;
    float* Q1  = ws + OFF_Q1;
    float* Q2  = ws + OFF_Q2;
    float* Q3  = ws + OFF_Q3;
    float* K2v = ws + OFF_K2;
    float* N0  = ws + OFF_N0;
    float* H1  = ws + OFF_H1;
    float* H2  = ws + OFF_H2;
    unsigned* flags = (unsigned*)(ws + OFF_FLG);

    // zero flag lines + release word (epochs are monotonic within one launch)
    hipMemsetAsync(flags, 0, (NWG * FLAG_STRIDE + 16) * sizeof(unsigned), stream);

    // out[:, :2048, :] = x
    copy_x_kernel<<<4096, 256, 0, stream>>>((const float4*)x, (float4*)out);

    // precompute E, Q1, Q2, Q3, K2
    gemm_E_kernel<<<dim3(16, 8), 256, 0, stream>>>(D2, W1, E);
    qk_kernel<<<162, 256, 0, stream>>>(Bm, D1, W1, b1, bD2, Q1, Q2, Q3, K2v);

    // persistent recurrence kernel: 256 WGs (1/CU, forced by LDS usage)
    (void)hipFuncSetAttribute((const void*)main_kernel,
                              hipFuncAttributeMaxDynamicSharedMemorySize, SMEM_BYTES);
    main_kernel<<<NWG, TPB, SMEM_BYTES, stream>>>(
        x, Bm, W1, b1, W2, b2, D1, bD1, D2, bD2, out,
        E, Q1, Q2, Q3, K2v, N0, H1, H2, flags);
}